// Round 1
// baseline (4068.470 us; speedup 1.0000x reference)
//
#include <hip/hip_runtime.h>
#include <stdint.h>

#define T_TOK 4096
#define HDIM  1024
#define FDIM  4096
#define F2DIM 2048

typedef __attribute__((ext_vector_type(4))) float f32x4;
typedef __attribute__((ext_vector_type(8))) short bf16x8;

__device__ __forceinline__ short f2bf(float x) {
  unsigned u = __float_as_uint(x);
  unsigned r = (u + 0x7fffu + ((u >> 16) & 1u)) >> 16;
  return (short)r;
}
__device__ __forceinline__ float bf2f(short s) {
  return __uint_as_float(((unsigned)(unsigned short)s) << 16);
}
__device__ __forceinline__ float gelu_exact(float x) {
  return 0.5f * x * (1.0f + erff(x * 0.70710678118654752440f));
}

#define GLDS16(gp, lp)                                                         \
  __builtin_amdgcn_global_load_lds(                                            \
      (const __attribute__((address_space(1))) void*)(gp),                     \
      (__attribute__((address_space(3))) void*)(lp), 16, 0, 0)

// ---------------------------------------------------------------------------
// K1: LayerNorm + router (softmax -> top2 -> renorm) + y = x init
// ---------------------------------------------------------------------------
__global__ __launch_bounds__(256) void ln_router(
    const float* __restrict__ X, const float* __restrict__ G,
    const float* __restrict__ Bb, const float* __restrict__ RW,
    short* __restrict__ NXh, short* __restrict__ NXl,
    float* __restrict__ Wout, float* __restrict__ Y)
{
  const int t = blockIdx.x, tid = threadIdx.x;
  const int lane = tid & 63, wid = tid >> 6;
  const float* xr = X + (size_t)t * HDIM;
  float v[4];
  float sum = 0.f, sq = 0.f;
#pragma unroll
  for (int i = 0; i < 4; ++i) {
    v[i] = xr[tid + i * 256];
    sum += v[i];
    sq += v[i] * v[i];
  }
#pragma unroll
  for (int o = 32; o > 0; o >>= 1) {
    sum += __shfl_down(sum, o);
    sq += __shfl_down(sq, o);
  }
  __shared__ float red[8];
  if (lane == 0) { red[wid] = sum; red[4 + wid] = sq; }
  __syncthreads();
  sum = red[0] + red[1] + red[2] + red[3];
  sq  = red[4] + red[5] + red[6] + red[7];
  const float mean = sum * (1.0f / HDIM);
  const float var  = sq * (1.0f / HDIM) - mean * mean;
  const float rstd = rsqrtf(var + 1e-5f);

  float lg[8];
#pragma unroll
  for (int e = 0; e < 8; ++e) lg[e] = 0.f;
#pragma unroll
  for (int i = 0; i < 4; ++i) {
    const int c = tid + i * 256;
    const float nx = (v[i] - mean) * rstd * G[c] + Bb[c];
    Y[(size_t)t * HDIM + c] = v[i];           // residual init: y = x
    short hh = f2bf(nx);
    NXh[(size_t)t * HDIM + c] = hh;
    NXl[(size_t)t * HDIM + c] = f2bf(nx - bf2f(hh));
#pragma unroll
    for (int e = 0; e < 8; ++e) lg[e] += nx * RW[c * 8 + e];
  }
#pragma unroll
  for (int e = 0; e < 8; ++e)
#pragma unroll
    for (int o = 32; o > 0; o >>= 1) lg[e] += __shfl_down(lg[e], o);
  __shared__ float rl[4][8];
  if (lane == 0)
    for (int e = 0; e < 8; ++e) rl[wid][e] = lg[e];
  __syncthreads();
  if (tid == 0) {
    float L[8];
    for (int e = 0; e < 8; ++e) L[e] = rl[0][e] + rl[1][e] + rl[2][e] + rl[3][e];
    float mx = L[0];
    for (int e = 1; e < 8; ++e) mx = fmaxf(mx, L[e]);
    float p[8], sp = 0.f;
    for (int e = 0; e < 8; ++e) { p[e] = expf(L[e] - mx); sp += p[e]; }
    for (int e = 0; e < 8; ++e) p[e] /= sp;
    int i1 = 0;
    for (int e = 1; e < 8; ++e) if (p[e] > p[i1]) i1 = e;    // ties -> lowest idx
    int i2 = (i1 == 0) ? 1 : 0;
    for (int e = 0; e < 8; ++e) if (e != i1 && p[e] > p[i2]) i2 = e;
    const float s2 = p[i1] + p[i2];
    float wrow[8];
    for (int e = 0; e < 8; ++e) wrow[e] = 0.f;
    wrow[i1] = p[i1] / s2;
    wrow[i2] = p[i2] / s2;
    for (int e = 0; e < 8; ++e) Wout[t * 8 + e] = wrow[e];
  }
}

__global__ void zero_cnt(int* cnt) {
  if (threadIdx.x < 8) cnt[threadIdx.x] = 0;
}

__global__ void build_lists(const float* __restrict__ wbuf, int* __restrict__ cnt,
                            int* __restrict__ tok, float* __restrict__ wgt)
{
  int t = blockIdx.x * blockDim.x + threadIdx.x;
  if (t >= T_TOK) return;
#pragma unroll
  for (int e = 0; e < 8; ++e) {
    float wv = wbuf[t * 8 + e];
    if (wv > 0.f) {
      int p = atomicAdd(&cnt[e], 1);
      tok[e * T_TOK + p] = t;
      wgt[e * T_TOK + p] = wv;
    }
  }
}

// ---------------------------------------------------------------------------
// Weight transpose + fp32 -> (bf16 hi, bf16 lo) convert: W[K][N] -> T[N][K]
// ---------------------------------------------------------------------------
__global__ __launch_bounds__(256) void wprep(
    const float* __restrict__ W, const int K, const int N,
    short* __restrict__ Th, short* __restrict__ Tl)
{
  __shared__ float tile[64][65];
  const int n0 = blockIdx.x * 64, k0 = blockIdx.y * 64;
  const int tid = threadIdx.x;
  {
    const int tn = tid & 63, tk4 = tid >> 6;
#pragma unroll
    for (int i = 0; i < 16; ++i) {
      const int k = tk4 * 16 + i;
      tile[k][tn] = W[(size_t)(k0 + k) * N + n0 + tn];
    }
  }
  __syncthreads();
  {
    const int tk = tid & 63, tn4 = tid >> 6;
#pragma unroll
    for (int i = 0; i < 16; ++i) {
      const int n = tn4 * 16 + i;
      const float val = tile[tk][n];
      const short h = f2bf(val);
      const short l = f2bf(val - bf2f(h));
      Th[(size_t)(n0 + n) * K + k0 + tk] = h;
      Tl[(size_t)(n0 + n) * K + k0 + tk] = l;
    }
  }
}

// ---------------------------------------------------------------------------
// Split-bf16 GEMM: C[M,N] = A[M,K] * B[N,K]^T  (3-product hi/lo correction)
// EPI 0: out = gelu(acc + bias) -> (Oh, Ol) bf16 pair
// EPI 1: out = acc + bias       -> Of fp32
// EPI 2: Y[tok[r]] += wgt[r] * (acc + bias)   (scatter-add, skip r >= cnt)
// ---------------------------------------------------------------------------
template <int TM, int TN, int EPI, bool GATHER>
__global__ __launch_bounds__(256) void gemm3k(
    const short* __restrict__ Ah, const short* __restrict__ Al, const int K,
    const short* __restrict__ Bh, const short* __restrict__ Bl, const int N,
    const int* __restrict__ cntp, const int* __restrict__ tokp,
    const float* __restrict__ wgtp, const float* __restrict__ bias,
    short* __restrict__ Oh, short* __restrict__ Ol,
    float* __restrict__ Of, float* __restrict__ Y)
{
  const int cnt = *cntp;
  const int mt = blockIdx.x, nt = blockIdx.y;
  if (mt * TM >= cnt) return;
  const int tid = threadIdx.x;
  const int lane = tid & 63, wid = tid >> 6;
  const int wr = wid >> 1, wc = wid & 1;            // 2x2 waves
  constexpr int WM = TM / 2, WN = TN / 2;
  constexpr int FM = WM / 16, FN = WN / 16;
  constexpr int ITA = (TM * 4) / 256;
  constexpr int ITB = (TN * 4) / 256;

  __shared__ short As_h[TM * 32], As_l[TM * 32];
  __shared__ short Bs_h[TN * 32], Bs_l[TN * 32];

  const int g = lane >> 4, r = lane & 15;

  const short* pAh[ITA];
  const short* pAl[ITA];
  int lA[ITA];
#pragma unroll
  for (int j = 0; j < ITA; ++j) {
    const int s = j * 256 + tid;
    const int row = s >> 2, seg = s & 3;
    int gr = mt * TM + row;
    if (GATHER) gr = (gr < cnt) ? tokp[gr] : 0;
    const size_t off = (size_t)gr * K + seg * 8;
    pAh[j] = Ah + off;
    pAl[j] = Al + off;
    lA[j] = (j * 256 + (wid << 6)) * 16;            // wave-uniform LDS byte base
  }
  const short* pBh[ITB];
  const short* pBl[ITB];
  int lB[ITB];
#pragma unroll
  for (int j = 0; j < ITB; ++j) {
    const int s = j * 256 + tid;
    const int row = s >> 2, seg = s & 3;
    const size_t off = (size_t)(nt * TN + row) * K + seg * 8;
    pBh[j] = Bh + off;
    pBl[j] = Bl + off;
    lB[j] = (j * 256 + (wid << 6)) * 16;
  }

  f32x4 acc[FM][FN];
#pragma unroll
  for (int m = 0; m < FM; ++m)
#pragma unroll
    for (int n = 0; n < FN; ++n) acc[m][n] = (f32x4){0.f, 0.f, 0.f, 0.f};

  for (int k0 = 0; k0 < K; k0 += 32) {
    __syncthreads();
#pragma unroll
    for (int j = 0; j < ITA; ++j) {
      GLDS16(pAh[j] + k0, (char*)As_h + lA[j]);
      GLDS16(pAl[j] + k0, (char*)As_l + lA[j]);
    }
#pragma unroll
    for (int j = 0; j < ITB; ++j) {
      GLDS16(pBh[j] + k0, (char*)Bs_h + lB[j]);
      GLDS16(pBl[j] + k0, (char*)Bs_l + lB[j]);
    }
    __syncthreads();

    bf16x8 ah[FM], al[FM], bh[FN], bl[FN];
#pragma unroll
    for (int m = 0; m < FM; ++m) {
      const int row = wr * WM + m * 16 + r;
      ah[m] = *(const bf16x8*)&As_h[row * 32 + g * 8];
      al[m] = *(const bf16x8*)&As_l[row * 32 + g * 8];
    }
#pragma unroll
    for (int n = 0; n < FN; ++n) {
      const int col = wc * WN + n * 16 + r;
      bh[n] = *(const bf16x8*)&Bs_h[col * 32 + g * 8];
      bl[n] = *(const bf16x8*)&Bs_l[col * 32 + g * 8];
    }
#pragma unroll
    for (int m = 0; m < FM; ++m)
#pragma unroll
      for (int n = 0; n < FN; ++n) {
        acc[m][n] = __builtin_amdgcn_mfma_f32_16x16x32_bf16(ah[m], bh[n], acc[m][n], 0, 0, 0);
        acc[m][n] = __builtin_amdgcn_mfma_f32_16x16x32_bf16(ah[m], bl[n], acc[m][n], 0, 0, 0);
        acc[m][n] = __builtin_amdgcn_mfma_f32_16x16x32_bf16(al[m], bh[n], acc[m][n], 0, 0, 0);
      }
  }

  // epilogue: C/D layout col = lane&15, row = (lane>>4)*4 + reg  [m89-verified]
#pragma unroll
  for (int m = 0; m < FM; ++m) {
#pragma unroll
    for (int jj = 0; jj < 4; ++jj) {
      const int rl_ = wr * WM + m * 16 + g * 4 + jj;
      const int R = mt * TM + rl_;
      if constexpr (EPI == 2) {
        if (R < cnt) {
          const int t = tokp[R];
          const float wv = wgtp[R];
#pragma unroll
          for (int n = 0; n < FN; ++n) {
            const int C = nt * TN + wc * WN + n * 16 + r;
            const float v = acc[m][n][jj] + bias[C];
            Y[(size_t)t * N + C] += wv * v;
          }
        }
      } else {
        const size_t rowoff = (size_t)R * N;
#pragma unroll
        for (int n = 0; n < FN; ++n) {
          const int C = nt * TN + wc * WN + n * 16 + r;
          const float v = acc[m][n][jj] + bias[C];
          if constexpr (EPI == 0) {
            const float gv = gelu_exact(v);
            const short hh = f2bf(gv);
            Oh[rowoff + C] = hh;
            Ol[rowoff + C] = f2bf(gv - bf2f(hh));
          } else {
            Of[rowoff + C] = v;
          }
        }
      }
    }
  }
}

// ---------------------------------------------------------------------------
// Row LayerNorm (over F=4096) + optional GELU, fp32 in -> bf16 hi/lo out
// ---------------------------------------------------------------------------
__global__ __launch_bounds__(256) void ln_rows(
    const float* __restrict__ S, const float* __restrict__ G,
    const float* __restrict__ Bb, const int gelu_f,
    const int* __restrict__ cntp, short* __restrict__ Oh, short* __restrict__ Ol)
{
  const int cnt = *cntp;
  const int lim = (cnt + 63) & ~63;
  const int row = blockIdx.x;
  if (row >= lim) return;
  const int tid = threadIdx.x, lane = tid & 63, wid = tid >> 6;
  const float* sr = S + (size_t)row * FDIM;
  float v[16];
  float sum = 0.f, sq = 0.f;
#pragma unroll
  for (int i = 0; i < 16; ++i) {
    v[i] = sr[tid + i * 256];
    sum += v[i];
    sq += v[i] * v[i];
  }
#pragma unroll
  for (int o = 32; o > 0; o >>= 1) {
    sum += __shfl_down(sum, o);
    sq += __shfl_down(sq, o);
  }
  __shared__ float red[8];
  if (lane == 0) { red[wid] = sum; red[4 + wid] = sq; }
  __syncthreads();
  sum = red[0] + red[1] + red[2] + red[3];
  sq  = red[4] + red[5] + red[6] + red[7];
  const float mean = sum * (1.0f / FDIM);
  const float var  = sq * (1.0f / FDIM) - mean * mean;
  const float rstd = rsqrtf(var + 1e-5f);
#pragma unroll
  for (int i = 0; i < 16; ++i) {
    const int c = tid + i * 256;
    float x = (v[i] - mean) * rstd * G[c] + Bb[c];
    if (gelu_f) x = gelu_exact(x);
    const short hh = f2bf(x);
    Oh[(size_t)row * FDIM + c] = hh;
    Ol[(size_t)row * FDIM + c] = f2bf(x - bf2f(hh));
  }
}

// ---------------------------------------------------------------------------
extern "C" void kernel_launch(void* const* d_in, const int* in_sizes, int n_in,
                              void* d_out, int out_size, void* d_ws, size_t ws_size,
                              hipStream_t stream)
{
  const float* X    = (const float*)d_in[0];
  const float* LNG  = (const float*)d_in[1];
  const float* LNB  = (const float*)d_in[2];
  const float* RW   = (const float*)d_in[3];
  const float* UPW  = (const float*)d_in[4];
  const float* UPB  = (const float*)d_in[5];
  const float* DNW  = (const float*)d_in[6];
  const float* DNB  = (const float*)d_in[7];
  const float* S0W  = (const float*)d_in[8];
  const float* S0B  = (const float*)d_in[9];
  const float* L0G  = (const float*)d_in[10];
  const float* L0B  = (const float*)d_in[11];
  const float* S1AW = (const float*)d_in[12];
  const float* S1AB = (const float*)d_in[13];
  const float* S1BW = (const float*)d_in[14];
  const float* S1BB = (const float*)d_in[15];
  const float* L1G  = (const float*)d_in[16];
  const float* L1B  = (const float*)d_in[17];
  const float* S2W  = (const float*)d_in[18];
  const float* S2B  = (const float*)d_in[19];
  float* Y = (float*)d_out;

  size_t off = 0;
  char* base = (char*)d_ws;
  auto alloc = [&](size_t bytes) -> char* {
    char* p = base + off;
    off += (bytes + 255) & ~(size_t)255;
    return p;
  };
  short* nxh  = (short*)alloc((size_t)T_TOK * HDIM * 2);
  short* nxl  = (short*)alloc((size_t)T_TOK * HDIM * 2);
  float* wbuf = (float*)alloc((size_t)T_TOK * 8 * 4);
  int*   cnt  = (int*)alloc(64);
  int*   tok  = (int*)alloc((size_t)8 * T_TOK * 4);
  float* wgt  = (float*)alloc((size_t)8 * T_TOK * 4);
  short* Wth  = (short*)alloc((size_t)FDIM * FDIM * 2);
  short* Wtl  = (short*)alloc((size_t)FDIM * FDIM * 2);
  short* h1h  = (short*)alloc((size_t)T_TOK * FDIM * 2);
  short* h1l  = (short*)alloc((size_t)T_TOK * FDIM * 2);
  short* h2h  = (short*)alloc((size_t)T_TOK * FDIM * 2);
  short* h2l  = (short*)alloc((size_t)T_TOK * FDIM * 2);
  short* t1h  = (short*)alloc((size_t)T_TOK * F2DIM * 2);
  short* t1l  = (short*)alloc((size_t)T_TOK * F2DIM * 2);
  float* sbuf = (float*)alloc((size_t)T_TOK * FDIM * 4);
  (void)ws_size; (void)in_sizes; (void)n_in; (void)out_size;

  zero_cnt<<<1, 32, 0, stream>>>(cnt);
  ln_router<<<T_TOK, 256, 0, stream>>>(X, LNG, LNB, RW, nxh, nxl, wbuf, Y);
  build_lists<<<T_TOK / 256, 256, 0, stream>>>(wbuf, cnt, tok, wgt);

  for (int e = 0; e < 8; ++e) {
    const int u = e / 4;
    const int* ce = cnt + e;
    const int* te = tok + e * T_TOK;
    const float* we = wgt + e * T_TOK;
    const int ty = e & 3;

    // up: h1 = gelu(nx_gathered @ up_W[e] + up_b[e])
    wprep<<<dim3(FDIM / 64, HDIM / 64), 256, 0, stream>>>(
        UPW + (size_t)e * HDIM * FDIM, HDIM, FDIM, Wth, Wtl);
    gemm3k<64, 128, 0, true><<<dim3(T_TOK / 64, FDIM / 128), 256, 0, stream>>>(
        nxh, nxl, HDIM, Wth, Wtl, FDIM, ce, te, we,
        UPB + (size_t)e * FDIM, h1h, h1l, nullptr, nullptr);

    short* dh = h1h;
    short* dl = h1l;
    if (ty == 0) {
      wprep<<<dim3(FDIM / 64, FDIM / 64), 256, 0, stream>>>(
          S0W + (size_t)u * FDIM * FDIM, FDIM, FDIM, Wth, Wtl);
      gemm3k<64, 128, 1, false><<<dim3(T_TOK / 64, FDIM / 128), 256, 0, stream>>>(
          h1h, h1l, FDIM, Wth, Wtl, FDIM, ce, te, we,
          S0B + (size_t)u * FDIM, nullptr, nullptr, sbuf, nullptr);
      ln_rows<<<T_TOK, 256, 0, stream>>>(
          sbuf, L0G + (size_t)u * FDIM, L0B + (size_t)u * FDIM, 1, ce, h2h, h2l);
      dh = h2h; dl = h2l;
    } else if (ty == 1) {
      wprep<<<dim3(F2DIM / 64, FDIM / 64), 256, 0, stream>>>(
          S1AW + (size_t)u * FDIM * F2DIM, FDIM, F2DIM, Wth, Wtl);
      gemm3k<64, 64, 0, false><<<dim3(T_TOK / 64, F2DIM / 64), 256, 0, stream>>>(
          h1h, h1l, FDIM, Wth, Wtl, F2DIM, ce, te, we,
          S1AB + (size_t)u * F2DIM, t1h, t1l, nullptr, nullptr);
      wprep<<<dim3(FDIM / 64, F2DIM / 64), 256, 0, stream>>>(
          S1BW + (size_t)u * F2DIM * FDIM, F2DIM, FDIM, Wth, Wtl);
      gemm3k<64, 128, 1, false><<<dim3(T_TOK / 64, FDIM / 128), 256, 0, stream>>>(
          t1h, t1l, F2DIM, Wth, Wtl, FDIM, ce, te, we,
          S1BB + (size_t)u * FDIM, nullptr, nullptr, sbuf, nullptr);
      ln_rows<<<T_TOK, 256, 0, stream>>>(
          sbuf, L1G + (size_t)u * FDIM, L1B + (size_t)u * FDIM, 0, ce, h2h, h2l);
      dh = h2h; dl = h2l;
    } else if (ty == 2) {
      wprep<<<dim3(FDIM / 64, FDIM / 64), 256, 0, stream>>>(
          S2W + (size_t)u * FDIM * FDIM, FDIM, FDIM, Wth, Wtl);
      gemm3k<64, 128, 0, false><<<dim3(T_TOK / 64, FDIM / 128), 256, 0, stream>>>(
          h1h, h1l, FDIM, Wth, Wtl, FDIM, ce, te, we,
          S2B + (size_t)u * FDIM, h2h, h2l, nullptr, nullptr);
      dh = h2h; dl = h2l;
    }
    // ty == 3: identity, dh/dl stay = h1

    // down: y[tok[r]] += w[r] * (h2 @ down_W[e] + down_b[e])
    wprep<<<dim3(HDIM / 64, FDIM / 64), 256, 0, stream>>>(
        DNW + (size_t)e * FDIM * HDIM, FDIM, HDIM, Wth, Wtl);
    gemm3k<64, 64, 2, false><<<dim3(T_TOK / 64, HDIM / 64), 256, 0, stream>>>(
        dh, dl, FDIM, Wth, Wtl, HDIM, ce, te, we,
        DNB + (size_t)e * HDIM, nullptr, nullptr, nullptr, Y);
  }
}

// Round 2
// 2484.062 us; speedup vs baseline: 1.6378x; 1.6378x over previous
//
#include <hip/hip_runtime.h>
#include <stdint.h>

#define T_TOK 4096
#define HDIM  1024
#define FDIM  4096
#define F2DIM 2048
#define TM    128
#define TN    128
#define RCAP  9216   // 8192 rows + 8*128 pad
#define GXA   72     // worst-case m-tiles, all-expert stages
#define GXS   66     // worst-case m-tiles, 2-expert stages

typedef __attribute__((ext_vector_type(4))) float f32x4;
typedef __attribute__((ext_vector_type(8))) short bf16x8;

__device__ __forceinline__ short f2bf(float x) {
  unsigned u = __float_as_uint(x);
  unsigned r = (u + 0x7fffu + ((u >> 16) & 1u)) >> 16;
  return (short)r;
}
__device__ __forceinline__ float bf2f(short s) {
  return __uint_as_float(((unsigned)(unsigned short)s) << 16);
}
__device__ __forceinline__ float gelu_exact(float x) {
  return 0.5f * x * (1.0f + erff(x * 0.70710678118654752440f));
}

#define GLDS16(gp, lp)                                                         \
  __builtin_amdgcn_global_load_lds(                                            \
      (const __attribute__((address_space(1))) void*)(gp),                     \
      (__attribute__((address_space(3))) void*)(lp), 16, 0, 0)

// ---------------------------------------------------------------------------
// zero init: cnt[8], cur[8], tokc[RCAP]
// ---------------------------------------------------------------------------
__global__ void zeroinit(int* cnt, int* cur, int* tokc) {
  const int i = blockIdx.x * 256 + threadIdx.x;
  if (i < RCAP) tokc[i] = 0;
  if (i < 8) { cnt[i] = 0; cur[i] = 0; }
}

// ---------------------------------------------------------------------------
// K1: LayerNorm + router (softmax -> top2 -> renorm)
// ---------------------------------------------------------------------------
__global__ __launch_bounds__(256) void ln_router(
    const float* __restrict__ X, const float* __restrict__ G,
    const float* __restrict__ Bb, const float* __restrict__ RW,
    short* __restrict__ NXh, short* __restrict__ NXl, float* __restrict__ Wout)
{
  const int t = blockIdx.x, tid = threadIdx.x;
  const int lane = tid & 63, wid = tid >> 6;
  const float* xr = X + (size_t)t * HDIM;
  float v[4];
  float sum = 0.f, sq = 0.f;
#pragma unroll
  for (int i = 0; i < 4; ++i) {
    v[i] = xr[tid + i * 256];
    sum += v[i];
    sq += v[i] * v[i];
  }
#pragma unroll
  for (int o = 32; o > 0; o >>= 1) {
    sum += __shfl_down(sum, o);
    sq += __shfl_down(sq, o);
  }
  __shared__ float red[8];
  if (lane == 0) { red[wid] = sum; red[4 + wid] = sq; }
  __syncthreads();
  sum = red[0] + red[1] + red[2] + red[3];
  sq  = red[4] + red[5] + red[6] + red[7];
  const float mean = sum * (1.0f / HDIM);
  const float var  = sq * (1.0f / HDIM) - mean * mean;
  const float rstd = rsqrtf(var + 1e-5f);

  float lg[8];
#pragma unroll
  for (int e = 0; e < 8; ++e) lg[e] = 0.f;
#pragma unroll
  for (int i = 0; i < 4; ++i) {
    const int c = tid + i * 256;
    const float nx = (v[i] - mean) * rstd * G[c] + Bb[c];
    short hh = f2bf(nx);
    NXh[(size_t)t * HDIM + c] = hh;
    NXl[(size_t)t * HDIM + c] = f2bf(nx - bf2f(hh));
#pragma unroll
    for (int e = 0; e < 8; ++e) lg[e] += nx * RW[c * 8 + e];
  }
#pragma unroll
  for (int e = 0; e < 8; ++e)
#pragma unroll
    for (int o = 32; o > 0; o >>= 1) lg[e] += __shfl_down(lg[e], o);
  __shared__ float rl[4][8];
  if (lane == 0)
    for (int e = 0; e < 8; ++e) rl[wid][e] = lg[e];
  __syncthreads();
  if (tid == 0) {
    float L[8];
    for (int e = 0; e < 8; ++e) L[e] = rl[0][e] + rl[1][e] + rl[2][e] + rl[3][e];
    float mx = L[0];
    for (int e = 1; e < 8; ++e) mx = fmaxf(mx, L[e]);
    float p[8], sp = 0.f;
    for (int e = 0; e < 8; ++e) { p[e] = expf(L[e] - mx); sp += p[e]; }
    for (int e = 0; e < 8; ++e) p[e] /= sp;
    int i1 = 0;
    for (int e = 1; e < 8; ++e) if (p[e] > p[i1]) i1 = e;
    int i2 = (i1 == 0) ? 1 : 0;
    for (int e = 0; e < 8; ++e) if (e != i1 && p[e] > p[i2]) i2 = e;
    const float s2 = p[i1] + p[i2];
    float wrow[8];
    for (int e = 0; e < 8; ++e) wrow[e] = 0.f;
    wrow[i1] = p[i1] / s2;
    wrow[i2] = p[i2] / s2;
    for (int e = 0; e < 8; ++e) Wout[t * 8 + e] = wrow[e];
  }
}

__global__ void count_k(const float* __restrict__ wbuf, int* __restrict__ cnt) {
  const int t = blockIdx.x * 256 + threadIdx.x;
  if (t >= T_TOK) return;
#pragma unroll
  for (int e = 0; e < 8; ++e)
    if (wbuf[t * 8 + e] > 0.f) atomicAdd(&cnt[e], 1);
}

// single-thread: prefix offsets (TM-aligned) + per-stage work lists
__global__ void prefix_build(const int* __restrict__ cnt, int* __restrict__ off,
                             int4* __restrict__ WLA, int4* __restrict__ WL0,
                             int4* __restrict__ WL1, int4* __restrict__ WL2,
                             int* __restrict__ mcounts)
{
  if (threadIdx.x != 0 || blockIdx.x != 0) return;
  int o = 0, off_[8];
  for (int e = 0; e < 8; ++e) {
    off_[e] = o; off[e] = o;
    o += (cnt[e] + TM - 1) & ~(TM - 1);
  }
  off[8] = o;
  int na = 0, n0 = 0, n1 = 0, n2 = 0;
  for (int e = 0; e < 8; ++e) {
    const int tiles = (cnt[e] + TM - 1) / TM;
    const int ty = e & 3, u = e >> 2;
    for (int j = 0; j < tiles; ++j) {
      int4 en; en.x = off_[e] + j * TM; en.y = e; en.z = e; en.w = 0;
      WLA[na++] = en;
      int4 es = en; es.z = u;
      if (ty == 0) WL0[n0++] = es;
      else if (ty == 1) WL1[n1++] = es;
      else if (ty == 2) WL2[n2++] = es;
    }
  }
  mcounts[0] = na; mcounts[1] = n0; mcounts[2] = n1; mcounts[3] = n2;
}

__global__ void fill_k(const float* __restrict__ wbuf, const int* __restrict__ off,
                       int* __restrict__ cur, int* __restrict__ tokc,
                       int* __restrict__ invr, float* __restrict__ invw)
{
  const int t = blockIdx.x * 256 + threadIdx.x;
  if (t >= T_TOK) return;
  int j = 0;
#pragma unroll
  for (int e = 0; e < 8; ++e) {
    const float wv = wbuf[t * 8 + e];
    if (wv > 0.f) {
      const int p = atomicAdd(&cur[e], 1);
      const int R = off[e] + p;
      tokc[R] = t;
      invr[t * 2 + j] = R;
      invw[t * 2 + j] = wv;
      ++j;
    }
  }
}

// ---------------------------------------------------------------------------
// Batched weight transpose+convert: W[z][K][N] -> (Th,Tl)[z][N][K]
// ---------------------------------------------------------------------------
__global__ __launch_bounds__(256) void wprep(
    const float* __restrict__ W0, const int K, const int N,
    short* __restrict__ Th0, short* __restrict__ Tl0)
{
  const size_t z = blockIdx.z;
  const float* W = W0 + z * (size_t)K * N;
  short* Th = Th0 + z * (size_t)N * K;
  short* Tl = Tl0 + z * (size_t)N * K;
  __shared__ float tile[64][65];
  const int n0 = blockIdx.x * 64, k0 = blockIdx.y * 64;
  const int tid = threadIdx.x;
  {
    const int tn = tid & 63, tk4 = tid >> 6;
#pragma unroll
    for (int i = 0; i < 16; ++i) {
      const int k = tk4 * 16 + i;
      tile[k][tn] = W[(size_t)(k0 + k) * N + n0 + tn];
    }
  }
  __syncthreads();
  {
    const int tk = tid & 63, tn4 = tid >> 6;
#pragma unroll
    for (int i = 0; i < 16; ++i) {
      const int n = tn4 * 16 + i;
      const float val = tile[tk][n];
      const short h = f2bf(val);
      const short l = f2bf(val - bf2f(h));
      Th[(size_t)(n0 + n) * K + k0 + tk] = h;
      Tl[(size_t)(n0 + n) * K + k0 + tk] = l;
    }
  }
}

// ---------------------------------------------------------------------------
// Split-bf16 GEMM, 128x128 tile, m97 structure, work-list batched.
// EPI 0: gelu(acc+bias) -> bf16 pair   EPI 1: acc+bias -> fp32
// ---------------------------------------------------------------------------
template <int EPI, bool GATHER>
__global__ __launch_bounds__(256) void moe_gemm(
    const short* __restrict__ Ah, const short* __restrict__ Al, const int K,
    const short* __restrict__ Wh0, const short* __restrict__ Wl0, const int N,
    const int4* __restrict__ wlist, const int* __restrict__ mcp,
    const int* __restrict__ tokc, const float* __restrict__ bias0, const int GX,
    short* __restrict__ Oh, short* __restrict__ Ol, float* __restrict__ Of)
{
  const int mc = *mcp;
  // m204 bijective XCD swizzle on flattened grid (mt fastest -> share B-tile)
  const int nwg = gridDim.x, orig = blockIdx.x;
  const int q = nwg >> 3, rr = nwg & 7, xcd = orig & 7, rem = orig >> 3;
  const int wg = (xcd < rr ? xcd * (q + 1) : rr * (q + 1) + (xcd - rr) * q) + rem;
  const int mt = wg % GX, nt = wg / GX;
  if (mt >= mc) return;
  const int4 we = wlist[mt];
  const int row0 = we.x, bidx = we.z;
  const short* Wh = Wh0 + (size_t)bidx * N * K;
  const short* Wl = Wl0 + (size_t)bidx * N * K;
  const float* bias = bias0 + (size_t)bidx * N;

  const int tid = threadIdx.x, lane = tid & 63, wid = tid >> 6;
  const int wr = wid >> 1, wc = wid & 1;
  const int g = lane >> 4, r = lane & 15;

  __shared__ short As_h[TM * 32], As_l[TM * 32];
  __shared__ short Bs_h[TN * 32], Bs_l[TN * 32];

  const short *pAh[2], *pAl[2], *pBh[2], *pBl[2];
  int ldsO[2];
#pragma unroll
  for (int j = 0; j < 2; ++j) {
    const int s = j * 256 + tid;
    const int rowl = s >> 2, qq = s & 3;
    int gr = row0 + rowl;
    if (GATHER) gr = tokc[gr];
    const size_t offA = (size_t)gr * K + qq * 8;
    pAh[j] = Ah + offA;
    pAl[j] = Al + offA;
    const size_t offB = (size_t)(nt * TN + rowl) * K + qq * 8;
    pBh[j] = Wh + offB;
    pBl[j] = Wl + offB;
    ldsO[j] = (j * 256 + wid * 64) * 16;   // wave-uniform LDS byte base
  }

  f32x4 acc[4][4];
#pragma unroll
  for (int m = 0; m < 4; ++m)
#pragma unroll
    for (int n = 0; n < 4; ++n) acc[m][n] = (f32x4){0.f, 0.f, 0.f, 0.f};

  for (int k0 = 0; k0 < K; k0 += 32) {
    __syncthreads();
#pragma unroll
    for (int j = 0; j < 2; ++j) {
      GLDS16(pAh[j] + k0, (char*)As_h + ldsO[j]);
      GLDS16(pAl[j] + k0, (char*)As_l + ldsO[j]);
      GLDS16(pBh[j] + k0, (char*)Bs_h + ldsO[j]);
      GLDS16(pBl[j] + k0, (char*)Bs_l + ldsO[j]);
    }
    __syncthreads();

    bf16x8 ah[4], al[4], bh[4], bl[4];
#pragma unroll
    for (int m = 0; m < 4; ++m) {
      const int row = wr * 64 + m * 16 + r;
      ah[m] = *(const bf16x8*)&As_h[row * 32 + g * 8];
      al[m] = *(const bf16x8*)&As_l[row * 32 + g * 8];
    }
#pragma unroll
    for (int n = 0; n < 4; ++n) {
      const int col = wc * 64 + n * 16 + r;
      bh[n] = *(const bf16x8*)&Bs_h[col * 32 + g * 8];
      bl[n] = *(const bf16x8*)&Bs_l[col * 32 + g * 8];
    }
#pragma unroll
    for (int m = 0; m < 4; ++m)
#pragma unroll
      for (int n = 0; n < 4; ++n) {
        acc[m][n] = __builtin_amdgcn_mfma_f32_16x16x32_bf16(ah[m], bh[n], acc[m][n], 0, 0, 0);
        acc[m][n] = __builtin_amdgcn_mfma_f32_16x16x32_bf16(ah[m], bl[n], acc[m][n], 0, 0, 0);
        acc[m][n] = __builtin_amdgcn_mfma_f32_16x16x32_bf16(al[m], bh[n], acc[m][n], 0, 0, 0);
      }
  }

  // C/D layout: col = lane&15, row = (lane>>4)*4 + reg  [m89-verified]
#pragma unroll
  for (int m = 0; m < 4; ++m) {
#pragma unroll
    for (int jj = 0; jj < 4; ++jj) {
      const int R = row0 + wr * 64 + m * 16 + g * 4 + jj;
      const size_t ro = (size_t)R * N;
#pragma unroll
      for (int n = 0; n < 4; ++n) {
        const int C = nt * TN + wc * 64 + n * 16 + r;
        float v = acc[m][n][jj] + bias[C];
        if constexpr (EPI == 0) {
          v = gelu_exact(v);
          const short hh = f2bf(v);
          Oh[ro + C] = hh;
          Ol[ro + C] = f2bf(v - bf2f(hh));
        } else {
          Of[ro + C] = v;
        }
      }
    }
  }
}

// ---------------------------------------------------------------------------
// Row post-pass over sbuf rows of experts e0 (unit 0) / e1 (unit 1):
// mode 0: LN+GELU, mode 1: LN, mode 2: GELU. Writes bf16 pair into h1.
// ---------------------------------------------------------------------------
__global__ __launch_bounds__(256) void rowpost(
    const float* __restrict__ S, const float* __restrict__ G0,
    const float* __restrict__ B0, const int mode,
    const int* __restrict__ off, const int* __restrict__ cnt,
    const int e0, const int e1, short* __restrict__ Oh, short* __restrict__ Ol)
{
  const int row = blockIdx.x;
  const int o0 = off[e0], c0 = cnt[e0], o1 = off[e1], c1 = cnt[e1];
  int u;
  if (row >= o0 && row < o0 + c0) u = 0;
  else if (row >= o1 && row < o1 + c1) u = 1;
  else return;
  const int tid = threadIdx.x, lane = tid & 63, wid = tid >> 6;
  const float* sr = S + (size_t)row * FDIM;
  float v[16];
  float mean = 0.f, rstd = 1.f;
  if (mode < 2) {
    float sum = 0.f, sq = 0.f;
#pragma unroll
    for (int i = 0; i < 16; ++i) {
      v[i] = sr[tid + i * 256];
      sum += v[i];
      sq += v[i] * v[i];
    }
#pragma unroll
    for (int o = 32; o > 0; o >>= 1) {
      sum += __shfl_down(sum, o);
      sq += __shfl_down(sq, o);
    }
    __shared__ float red[8];
    if (lane == 0) { red[wid] = sum; red[4 + wid] = sq; }
    __syncthreads();
    sum = red[0] + red[1] + red[2] + red[3];
    sq  = red[4] + red[5] + red[6] + red[7];
    mean = sum * (1.0f / FDIM);
    const float var = sq * (1.0f / FDIM) - mean * mean;
    rstd = rsqrtf(var + 1e-5f);
  } else {
#pragma unroll
    for (int i = 0; i < 16; ++i) v[i] = sr[tid + i * 256];
  }
  const float* G = G0 + (size_t)u * FDIM;
  const float* Bb = B0 + (size_t)u * FDIM;
#pragma unroll
  for (int i = 0; i < 16; ++i) {
    const int c = tid + i * 256;
    float x = v[i];
    if (mode < 2) x = (x - mean) * rstd * G[c] + Bb[c];
    if (mode != 1) x = gelu_exact(x);
    const short hh = f2bf(x);
    Oh[(size_t)row * FDIM + c] = hh;
    Ol[(size_t)row * FDIM + c] = f2bf(x - bf2f(hh));
  }
}

// ---------------------------------------------------------------------------
// y[t] = x[t] + w0 * Dout[r0] + w1 * Dout[r1]
// ---------------------------------------------------------------------------
__global__ __launch_bounds__(256) void combine_k(
    const float* __restrict__ X, const float* __restrict__ Dout,
    const int* __restrict__ invr, const float* __restrict__ invw,
    float* __restrict__ Y)
{
  const int t = blockIdx.x;
  const int c = threadIdx.x * 4;
  const int r0 = invr[t * 2], r1 = invr[t * 2 + 1];
  const float w0 = invw[t * 2], w1 = invw[t * 2 + 1];
  const float4 x = *(const float4*)&X[(size_t)t * HDIM + c];
  const float4 a = *(const float4*)&Dout[(size_t)r0 * HDIM + c];
  const float4 b = *(const float4*)&Dout[(size_t)r1 * HDIM + c];
  float4 y;
  y.x = x.x + w0 * a.x + w1 * b.x;
  y.y = x.y + w0 * a.y + w1 * b.y;
  y.z = x.z + w0 * a.z + w1 * b.z;
  y.w = x.w + w0 * a.w + w1 * b.w;
  *(float4*)&Y[(size_t)t * HDIM + c] = y;
}

// ---------------------------------------------------------------------------
extern "C" void kernel_launch(void* const* d_in, const int* in_sizes, int n_in,
                              void* d_out, int out_size, void* d_ws, size_t ws_size,
                              hipStream_t stream)
{
  const float* X    = (const float*)d_in[0];
  const float* LNG  = (const float*)d_in[1];
  const float* LNB  = (const float*)d_in[2];
  const float* RW   = (const float*)d_in[3];
  const float* UPW  = (const float*)d_in[4];
  const float* UPB  = (const float*)d_in[5];
  const float* DNW  = (const float*)d_in[6];
  const float* DNB  = (const float*)d_in[7];
  const float* S0W  = (const float*)d_in[8];
  const float* S0B  = (const float*)d_in[9];
  const float* L0G  = (const float*)d_in[10];
  const float* L0B  = (const float*)d_in[11];
  const float* S1AW = (const float*)d_in[12];
  const float* S1AB = (const float*)d_in[13];
  const float* S1BW = (const float*)d_in[14];
  const float* S1BB = (const float*)d_in[15];
  const float* L1G  = (const float*)d_in[16];
  const float* L1B  = (const float*)d_in[17];
  const float* S2W  = (const float*)d_in[18];
  const float* S2B  = (const float*)d_in[19];
  float* Y = (float*)d_out;
  (void)in_sizes; (void)n_in; (void)out_size; (void)ws_size;

  size_t off_b = 0;
  char* base = (char*)d_ws;
  auto alloc = [&](size_t bytes) -> char* {
    char* p = base + off_b;
    off_b += (bytes + 255) & ~(size_t)255;
    return p;
  };
  short* nxh  = (short*)alloc((size_t)T_TOK * HDIM * 2);
  short* nxl  = (short*)alloc((size_t)T_TOK * HDIM * 2);
  float* wbuf = (float*)alloc((size_t)T_TOK * 8 * 4);
  int*   cnt  = (int*)alloc(64);
  int*   cur  = (int*)alloc(64);
  int*   off  = (int*)alloc(64);
  int*   mcts = (int*)alloc(64);
  int4*  WLA  = (int4*)alloc(256 * 16);
  int4*  WL0  = (int4*)alloc(128 * 16);
  int4*  WL1  = (int4*)alloc(128 * 16);
  int4*  WL2  = (int4*)alloc(128 * 16);
  int*   tokc = (int*)alloc((size_t)RCAP * 4);
  int*   invr = (int*)alloc((size_t)T_TOK * 2 * 4);
  float* invw = (float*)alloc((size_t)T_TOK * 2 * 4);
  short* Wth  = (short*)alloc((size_t)33554432 * 2);   // max stage: 33.55M elems
  short* Wtl  = (short*)alloc((size_t)33554432 * 2);
  short* h1h  = (short*)alloc((size_t)RCAP * FDIM * 2);
  short* h1l  = (short*)alloc((size_t)RCAP * FDIM * 2);
  short* t1h  = (short*)alloc((size_t)RCAP * F2DIM * 2);
  short* t1l  = (short*)alloc((size_t)RCAP * F2DIM * 2);
  float* sbuf = (float*)alloc((size_t)RCAP * FDIM * 4);
  float* Dout = sbuf;   // alias: Dout written after sbuf's last read (rowpost ty2)

  // --- routing ---
  zeroinit<<<(RCAP + 255) / 256, 256, 0, stream>>>(cnt, cur, tokc);
  ln_router<<<T_TOK, 256, 0, stream>>>(X, LNG, LNB, RW, nxh, nxl, wbuf);
  count_k<<<T_TOK / 256, 256, 0, stream>>>(wbuf, cnt);
  prefix_build<<<1, 64, 0, stream>>>(cnt, off, WLA, WL0, WL1, WL2, mcts);
  fill_k<<<T_TOK / 256, 256, 0, stream>>>(wbuf, off, cur, tokc, invr, invw);

  // --- U: h1 = gelu(gather(nx) @ up_W[e] + up_b[e]) ---
  wprep<<<dim3(FDIM / 64, HDIM / 64, 8), 256, 0, stream>>>(UPW, HDIM, FDIM, Wth, Wtl);
  moe_gemm<0, true><<<GXA * (FDIM / TN), 256, 0, stream>>>(
      nxh, nxl, HDIM, Wth, Wtl, FDIM, WLA, &mcts[0], tokc, UPB, GXA,
      h1h, h1l, nullptr);

  // --- S0 (ty0 experts 0,4): Linear -> (LN+GELU via rowpost) ---
  wprep<<<dim3(FDIM / 64, FDIM / 64, 2), 256, 0, stream>>>(S0W, FDIM, FDIM, Wth, Wtl);
  moe_gemm<1, false><<<GXS * (FDIM / TN), 256, 0, stream>>>(
      h1h, h1l, FDIM, Wth, Wtl, FDIM, WL0, &mcts[1], tokc, S0B, GXS,
      nullptr, nullptr, sbuf);
  rowpost<<<RCAP, 256, 0, stream>>>(sbuf, L0G, L0B, 0, off, cnt, 0, 4, h1h, h1l);

  // --- S1 (ty1 experts 1,5): Linear(F->F/2)+GELU, Linear(F/2->F) -> LN ---
  wprep<<<dim3(F2DIM / 64, FDIM / 64, 2), 256, 0, stream>>>(S1AW, FDIM, F2DIM, Wth, Wtl);
  moe_gemm<0, false><<<GXS * (F2DIM / TN), 256, 0, stream>>>(
      h1h, h1l, FDIM, Wth, Wtl, F2DIM, WL1, &mcts[2], tokc, S1AB, GXS,
      t1h, t1l, nullptr);
  wprep<<<dim3(FDIM / 64, F2DIM / 64, 2), 256, 0, stream>>>(S1BW, F2DIM, FDIM, Wth, Wtl);
  moe_gemm<1, false><<<GXS * (FDIM / TN), 256, 0, stream>>>(
      t1h, t1l, F2DIM, Wth, Wtl, FDIM, WL1, &mcts[2], tokc, S1BB, GXS,
      nullptr, nullptr, sbuf);
  rowpost<<<RCAP, 256, 0, stream>>>(sbuf, L1G, L1B, 1, off, cnt, 1, 5, h1h, h1l);

  // --- S2 (ty2 experts 2,6): Linear -> (GELU via rowpost) ---
  wprep<<<dim3(FDIM / 64, FDIM / 64, 2), 256, 0, stream>>>(S2W, FDIM, FDIM, Wth, Wtl);
  moe_gemm<1, false><<<GXS * (FDIM / TN), 256, 0, stream>>>(
      h1h, h1l, FDIM, Wth, Wtl, FDIM, WL2, &mcts[3], tokc, S2B, GXS,
      nullptr, nullptr, sbuf);
  rowpost<<<RCAP, 256, 0, stream>>>(sbuf, nullptr, nullptr, 2, off, cnt, 2, 6, h1h, h1l);

  // --- D: Dout = h1 @ down_W[e] + down_b[e] ---
  wprep<<<dim3(HDIM / 64, FDIM / 64, 8), 256, 0, stream>>>(DNW, FDIM, HDIM, Wth, Wtl);
  moe_gemm<1, false><<<GXA * (HDIM / TN), 256, 0, stream>>>(
      h1h, h1l, FDIM, Wth, Wtl, HDIM, WLA, &mcts[0], tokc, DNB, GXA,
      nullptr, nullptr, Dout);

  // --- combine: y = x + w0*Dout[r0] + w1*Dout[r1] ---
  combine_k<<<T_TOK, 256, 0, stream>>>(X, Dout, invr, invw, Y);
}